// Round 1
// baseline (79.311 us; speedup 1.0000x reference)
//
#include <hip/hip_runtime.h>
#include <math.h>

#define N 512
#define BATCH 256
#define KTOP 16
#define NLAYERS 45
#define NPAIRS 256

// One workgroup per batch element.
// Phase 1 (forward): evolve x[512] through the 45 bitonic compare-swap layers,
//   recording alpha per pair in LDS (45*256 floats = 46 KB).
// Phase 2 (backward): out row kk = row (511-kk) of L45*...*L1*I. Propagate the
//   one-hot row vector through layers in reverse; per-pair matrix is symmetric,
//   so update is v[i] = al*v[i] + (1-al)*v[i^j]. v lives in registers:
//   4 waves x 4 rows/wave, 8 floats/lane.
__global__ __launch_bounds__(256, 1)
void difftopk_kernel(const float* __restrict__ x_in, float* __restrict__ out) {
    __shared__ float xs[N];
    __shared__ float As[NLAYERS * NPAIRS];

    const int b   = blockIdx.x;
    const int tid = threadIdx.x;

    xs[tid]       = x_in[(size_t)b * N + tid];
    xs[tid + 256] = x_in[(size_t)b * N + tid + 256];
    __syncthreads();

    // ---------------- forward: evolve x, record alphas ----------------
    int t = 0;
    for (int k = 2; k <= N; k <<= 1) {
        for (int j = k >> 1; j >= 1; j >>= 1) {
            // thread tid handles pair ordinal tid: i = insert 0-bit at lg(j)
            const int low = tid & (j - 1);
            const int i   = ((tid ^ low) << 1) | low;  // (tid & ~(j-1))<<1 | low
            const int p   = i | j;
            int left, right;
            if ((i & k) == 0) { left = i; right = p; }
            else              { left = p; right = i; }
            const float a = xs[left];
            const float c = xs[right];
            const float alpha = atanf((c - a) * 10.0f) * 0.3183098861837907f + 0.5f;
            As[t * NPAIRS + tid] = alpha;
            // pairs are disjoint within a layer: no cross-thread hazard
            xs[left]  = alpha * a + (1.0f - alpha) * c;
            xs[right] = alpha * c + (1.0f - alpha) * a;
            ++t;
            __syncthreads();
        }
    }

    // ---------------- backward: propagate top-K rows ----------------
    const int wave  = tid >> 6;
    const int lane  = tid & 63;
    const int lane8 = lane << 3;

    float v[4][8];
    #pragma unroll
    for (int c = 0; c < 4; ++c) {
        const int r = N - 1 - (wave * 4 + c);  // out[b,kk,:] = X[b, 511-kk, :]
        #pragma unroll
        for (int m = 0; m < 8; ++m) v[c][m] = (lane8 + m == r) ? 1.0f : 0.0f;
    }

    // reverse layer order: t = 44 .. 0
    #pragma unroll
    for (int kk_ = 9; kk_ >= 1; --kk_) {
        #pragma unroll
        for (int lg = 0; lg < kk_; ++lg) {
            const int j  = 1 << lg;
            const int tt = ((kk_ - 1) * kk_) / 2 + (kk_ - 1 - lg);
            float al[8];
            #pragma unroll
            for (int m = 0; m < 8; ++m) {
                const int i   = lane8 + m;
                const int ord = ((i >> (lg + 1)) << lg) | (i & (j - 1));
                al[m] = As[tt * NPAIRS + ord];
            }
            if (j >= 8) {
                const int lm = j >> 3;  // lane xor distance
                #pragma unroll
                for (int c = 0; c < 4; ++c) {
                    #pragma unroll
                    for (int m = 0; m < 8; ++m) {
                        const float part = __shfl_xor(v[c][m], lm, 64);
                        v[c][m] = al[m] * v[c][m] + (1.0f - al[m]) * part;
                    }
                }
            } else {
                #pragma unroll
                for (int c = 0; c < 4; ++c) {
                    float nv[8];
                    #pragma unroll
                    for (int m = 0; m < 8; ++m)
                        nv[m] = al[m] * v[c][m] + (1.0f - al[m]) * v[c][m ^ j];
                    #pragma unroll
                    for (int m = 0; m < 8; ++m) v[c][m] = nv[m];
                }
            }
        }
    }

    // ---------------- write out[b, kk, :] ----------------
    #pragma unroll
    for (int c = 0; c < 4; ++c) {
        const int kk = wave * 4 + c;
        float4* dst = (float4*)(out + ((size_t)b * KTOP + kk) * N + lane8);
        dst[0] = make_float4(v[c][0], v[c][1], v[c][2], v[c][3]);
        dst[1] = make_float4(v[c][4], v[c][5], v[c][6], v[c][7]);
    }
}

extern "C" void kernel_launch(void* const* d_in, const int* in_sizes, int n_in,
                              void* d_out, int out_size, void* d_ws, size_t ws_size,
                              hipStream_t stream) {
    const float* x = (const float*)d_in[0];
    float* out = (float*)d_out;
    difftopk_kernel<<<dim3(BATCH), dim3(256), 0, stream>>>(x, out);
}